// Round 1
// baseline (1583.814 us; speedup 1.0000x reference)
//
#include <hip/hip_runtime.h>
#include <hip/hip_bf16.h>

// Problem: B=4, L=2048, D=1024.
// kqv = X @ Wkqv^T + b   (8192 x 3072)
// S[b] = Q[b] @ K[b]^T * 1/32, masked cols >= valid_len[b] -> -1e6
// attn = softmax rows
// out = attn @ V ; out2[b, 2d+(q>>10), q&1023] = out[b,q,d]  (swapaxes+reshape, L=2D)
// final = out2 @ Wproj^T + bproj

#define BM 128
#define BN 128
#define BK 16
#define LDSP 132  // padded leading dim (132*4 bytes = 16B aligned rows)

// NT: B is (N,K) row-major (we do A.B^T). If !NT, B is (K,N) row-major.
// MASK: scores epilogue: c = (n >= vlen[b]) ? -1e6 : c*scale
// BIAS: c += bias[n]
// PERM: write C at out2 permuted index (m=q, n=d)
template <bool NT, bool BIAS, bool MASK, bool PERM>
__global__ __launch_bounds__(256) void gemm_kernel(
    const float* __restrict__ A, long lda,
    const float* __restrict__ B, long ldb,
    float* __restrict__ C, long ldc,
    const float* __restrict__ bias,
    const int* __restrict__ valid_lens,
    float scale, int M, int N, int K,
    long strideA, long strideB, long strideC) {
  const int tid = threadIdx.x;
  const int tx = tid & 15;   // 0..15 -> N
  const int ty = tid >> 4;   // 0..15 -> M
  const int m0 = blockIdx.y * BM;
  const int n0 = blockIdx.x * BN;
  const int b = blockIdx.z;

  A += (long)b * strideA;
  B += (long)b * strideB;

  __shared__ float As[BK][LDSP];
  __shared__ float Bs[BK][LDSP];

  float acc[8][8];
#pragma unroll
  for (int i = 0; i < 8; ++i)
#pragma unroll
    for (int j = 0; j < 8; ++j) acc[i][j] = 0.0f;

  for (int k0 = 0; k0 < K; k0 += BK) {
    // ---- load A tile (BM x BK), store transposed As[k][m]
#pragma unroll
    for (int r = 0; r < 2; ++r) {
      const int f = tid + r * 256;       // 0..511 float4 index
      const int row = f >> 2;            // 0..127
      const int kq = (f & 3) * 4;        // 0,4,8,12
      const float4 v = *reinterpret_cast<const float4*>(
          &A[(long)(m0 + row) * lda + k0 + kq]);
      As[kq + 0][row] = v.x;
      As[kq + 1][row] = v.y;
      As[kq + 2][row] = v.z;
      As[kq + 3][row] = v.w;
    }
    // ---- load B tile -> Bs[k][n]
    if (NT) {
#pragma unroll
      for (int r = 0; r < 2; ++r) {
        const int f = tid + r * 256;
        const int row = f >> 2;          // n index 0..127
        const int kq = (f & 3) * 4;
        const float4 v = *reinterpret_cast<const float4*>(
            &B[(long)(n0 + row) * ldb + k0 + kq]);
        Bs[kq + 0][row] = v.x;
        Bs[kq + 1][row] = v.y;
        Bs[kq + 2][row] = v.z;
        Bs[kq + 3][row] = v.w;
      }
    } else {
#pragma unroll
      for (int r = 0; r < 2; ++r) {
        const int f = tid + r * 256;
        const int kk = f >> 5;           // 0..15
        const int n4 = (f & 31) * 4;     // 0..124
        const float4 v = *reinterpret_cast<const float4*>(
            &B[(long)(k0 + kk) * ldb + n0 + n4]);
        *reinterpret_cast<float4*>(&Bs[kk][n4]) = v;
      }
    }
    __syncthreads();

#pragma unroll
    for (int kk = 0; kk < BK; ++kk) {
      float a[8], bb[8];
#pragma unroll
      for (int i = 0; i < 8; ++i) a[i] = As[kk][ty * 8 + i];
#pragma unroll
      for (int j = 0; j < 8; ++j) bb[j] = Bs[kk][tx * 8 + j];
#pragma unroll
      for (int i = 0; i < 8; ++i)
#pragma unroll
        for (int j = 0; j < 8; ++j) acc[i][j] = fmaf(a[i], bb[j], acc[i][j]);
    }
    __syncthreads();
  }

  // ---- epilogue
  const int vlen = MASK ? valid_lens[b] : 0;
#pragma unroll
  for (int i = 0; i < 8; ++i) {
    const int m = m0 + ty * 8 + i;
#pragma unroll
    for (int j = 0; j < 8; ++j) {
      const int n = n0 + tx * 8 + j;
      float c = acc[i][j];
      if (MASK) c = (n >= vlen) ? -1000000.0f : c * scale;
      if (BIAS) c += bias[n];
      if (PERM) {
        // m = q in [0,2048), n = d in [0,1024)
        const long idx =
            (long)b * strideC + (long)(2 * n + (m >> 10)) * 1024 + (m & 1023);
        C[idx] = c;
      } else {
        C[(long)b * strideC + (long)m * ldc + n] = c;
      }
    }
  }
}

__global__ __launch_bounds__(256) void softmax_rows(float* __restrict__ S) {
  const long row = blockIdx.x;
  float* p = S + row * 2048;
  const int tid = threadIdx.x;
  const int wave = tid >> 6;
  const int lane = tid & 63;

  float4 a = *reinterpret_cast<float4*>(&p[tid * 8]);
  float4 bq = *reinterpret_cast<float4*>(&p[tid * 8 + 4]);

  float mx = fmaxf(fmaxf(fmaxf(a.x, a.y), fmaxf(a.z, a.w)),
                   fmaxf(fmaxf(bq.x, bq.y), fmaxf(bq.z, bq.w)));
#pragma unroll
  for (int o = 1; o < 64; o <<= 1) mx = fmaxf(mx, __shfl_xor(mx, o));
  __shared__ float redm[4];
  if (lane == 0) redm[wave] = mx;
  __syncthreads();
  mx = fmaxf(fmaxf(redm[0], redm[1]), fmaxf(redm[2], redm[3]));

  a.x = expf(a.x - mx);
  a.y = expf(a.y - mx);
  a.z = expf(a.z - mx);
  a.w = expf(a.w - mx);
  bq.x = expf(bq.x - mx);
  bq.y = expf(bq.y - mx);
  bq.z = expf(bq.z - mx);
  bq.w = expf(bq.w - mx);

  float s = a.x + a.y + a.z + a.w + bq.x + bq.y + bq.z + bq.w;
#pragma unroll
  for (int o = 1; o < 64; o <<= 1) s += __shfl_xor(s, o);
  __shared__ float reds[4];
  if (lane == 0) reds[wave] = s;
  __syncthreads();
  s = reds[0] + reds[1] + reds[2] + reds[3];

  const float inv = 1.0f / s;
  a.x *= inv; a.y *= inv; a.z *= inv; a.w *= inv;
  bq.x *= inv; bq.y *= inv; bq.z *= inv; bq.w *= inv;

  *reinterpret_cast<float4*>(&p[tid * 8]) = a;
  *reinterpret_cast<float4*>(&p[tid * 8 + 4]) = bq;
}

extern "C" void kernel_launch(void* const* d_in, const int* in_sizes, int n_in,
                              void* d_out, int out_size, void* d_ws,
                              size_t ws_size, hipStream_t stream) {
  const float* X = (const float*)d_in[0];      // (4,2048,1024)
  const int* vlens = (const int*)d_in[1];      // (4,)
  const float* Wkqv = (const float*)d_in[2];   // (3072,1024)
  const float* bkqv = (const float*)d_in[3];   // (3072,)
  const float* Wproj = (const float*)d_in[4];  // (1024,1024)
  const float* bproj = (const float*)d_in[5];  // (1024,)
  float* out = (float*)d_out;                  // (4,2048,1024)

  float* ws = (float*)d_ws;
  float* kqv = ws;                       // 8192*3072 f32
  float* S = kqv + 8192L * 3072;         // 4*2048*2048 f32
  float* out2 = S + 4L * 2048 * 2048;    // 8192*1024 f32

  const dim3 blk(256);

  // G1: kqv = X @ Wkqv^T + bkqv   (M=8192, N=3072, K=1024)
  gemm_kernel<true, true, false, false>
      <<<dim3(3072 / BN, 8192 / BM, 1), blk, 0, stream>>>(
          X, 1024, Wkqv, 1024, kqv, 3072, bkqv, nullptr, 1.0f, 8192, 3072,
          1024, 0, 0, 0);

  // G2: S[b] = Q[b] @ K[b]^T * 1/32, masked  (per batch M=N=2048, K=1024)
  gemm_kernel<true, false, true, false>
      <<<dim3(2048 / BN, 2048 / BM, 4), blk, 0, stream>>>(
          kqv + 1024, 3072, kqv, 3072, S, 2048, nullptr, vlens, 0.03125f, 2048,
          2048, 1024, 2048L * 3072, 2048L * 3072, 2048L * 2048);

  // G3: softmax rows (8192 rows of 2048)
  softmax_rows<<<dim3(4 * 2048), blk, 0, stream>>>(S);

  // G4: out2 = perm(attn @ V)  (per batch M=2048, N=1024, K=2048)
  gemm_kernel<false, false, false, true>
      <<<dim3(1024 / BN, 2048 / BM, 4), blk, 0, stream>>>(
          S, 2048, kqv + 2048, 3072, out2, 1024, nullptr, nullptr, 1.0f, 2048,
          1024, 2048, 2048L * 2048, 2048L * 3072, 2048L * 1024);

  // G5: out = out2 @ Wproj^T + bproj  (M=8192, N=1024, K=1024)
  gemm_kernel<true, true, false, false>
      <<<dim3(1024 / BN, 8192 / BM, 1), blk, 0, stream>>>(
          out2, 1024, Wproj, 1024, out, 1024, bproj, nullptr, 1.0f, 8192, 1024,
          1024, 0, 0, 0);
}

// Round 2
// 238.833 us; speedup vs baseline: 6.6315x; 6.6315x over previous
//
#include <hip/hip_runtime.h>
#include <hip/hip_fp16.h>

// B=4, L=2048, D=1024.  Pipeline (all GEMMs fp16-MFMA, f32 accumulate):
//  cvt:  X, Wkqv, Wproj -> fp16
//  G1:   kqvh = f16( Xh @ Wkqvh^T + bkqv )           (8192 x 3072)
//  G2:   S[b] = Qh @ Kh^T * 1/32, mask col>=vlen -> -1e6 (f32; fully-masked
//        128-col tiles skipped entirely)
//  SM:   softmax rows over cols < vlen, write attn fp16 (full 2048 cols)
//  G4:   out2h = f16( perm( attn @ V ) ), K-loop limited to ceil(vlen/32) tiles;
//        V staged with pack-transpose (V is K-major in kqvh)
//  G5:   out = out2h @ Wprojh^T + bproj  (f32 -> d_out)

typedef _Float16 f16;
typedef _Float16 f16x8 __attribute__((ext_vector_type(8)));
typedef float f32x4 __attribute__((ext_vector_type(4)));

#define BM 128
#define BN 128
#define BK 32

__device__ __forceinline__ void gload16(const f16* g, f16* l) {
  __builtin_amdgcn_global_load_lds(
      (const __attribute__((address_space(1))) unsigned int*)g,
      (__attribute__((address_space(3))) unsigned int*)l, 16, 0, 0);
}

// BT: B operand is V (K-major, reg-stage + pack-transpose). Otherwise B is
//     (N,K) row-major fp16, staged linearly via global_load_lds.
// BIAS: += bias[col] (f32). MASK: col>=vlen -> -1e6 else *scale; skip tile if
// n0>=vlen. PERM: write C[bz, 2*col + (row>>10), row&1023] (swapaxes-reshape).
// OUTF16: C is fp16 else f32. KLIM: K-loop limited to ceil(vlen/BK) tiles.
template <bool BT, bool BIAS, bool MASK, bool PERM, bool OUTF16, bool KLIM>
__global__ __launch_bounds__(256) void mfma_gemm(
    const f16* __restrict__ A, long lda, const f16* __restrict__ B, long ldb,
    void* __restrict__ Cv, long ldc, const float* __restrict__ bias,
    const int* __restrict__ valid_lens, float scale, int K, long strideA,
    long strideB, long strideC) {
  __shared__ __align__(16) f16 As[2][BM * BK];
  __shared__ __align__(16) f16 Bs[2][BN * BK];

  const int tid = threadIdx.x;
  const int w = tid >> 6;
  const int ln = tid & 63;
  const int m0 = blockIdx.y * BM;
  const int n0 = blockIdx.x * BN;
  const int bz = blockIdx.z;

  const int vlen = (MASK || KLIM) ? valid_lens[bz] : 0;
  if (MASK && n0 >= vlen) return;  // fully-masked tile: softmax never reads it

  A += (long)bz * strideA;
  B += (long)bz * strideB;

  int nk = K >> 5;
  if (KLIM) {
    int t = (vlen + BK - 1) >> 5;
    nk = t < nk ? t : nk;
  }

  // V pack-transpose staging indices
  const int kp = tid & 15;  // k-pair index (k = 2*kp, 2*kp+1)
  const int dg = tid >> 4;  // d-group (8 cols)

  f32x4 acc[4][4];
#pragma unroll
  for (int i = 0; i < 4; ++i)
#pragma unroll
    for (int j = 0; j < 4; ++j) acc[i][j] = (f32x4){0.f, 0.f, 0.f, 0.f};

  uint4 va, vb2;

  auto stageA = [&](int buf, int kk) {
#pragma unroll
    for (int r = 0; r < 2; ++r)
      gload16(A + (long)(m0 + r * 64 + w * 16 + (ln >> 2)) * lda + kk +
                  (ln & 3) * 8,
              &As[buf][(r * 64 + w * 16) * BK]);
  };
  auto stageB = [&](int buf, int kk) {
#pragma unroll
    for (int r = 0; r < 2; ++r)
      gload16(B + (long)(n0 + r * 64 + w * 16 + (ln >> 2)) * ldb + kk +
                  (ln & 3) * 8,
              &Bs[buf][(r * 64 + w * 16) * BK]);
  };
  auto loadV = [&](int kk) {
    const f16* p = B + (long)(kk + 2 * kp) * ldb + n0 + dg * 8;
    va = *(const uint4*)p;
    vb2 = *(const uint4*)(p + ldb);
  };
  auto writeV = [&](int buf) {
    unsigned int* bw = (unsigned int*)&Bs[buf][0];
    const unsigned int ax[4] = {va.x, va.y, va.z, va.w};
    const unsigned int bx[4] = {vb2.x, vb2.y, vb2.z, vb2.w};
#pragma unroll
    for (int j = 0; j < 4; ++j) {
      unsigned int lo = (ax[j] & 0xffffu) | (bx[j] << 16);
      unsigned int hi = (ax[j] >> 16) | (bx[j] & 0xffff0000u);
      bw[(dg * 8 + 2 * j) * 16 + kp] = lo;
      bw[(dg * 8 + 2 * j + 1) * 16 + kp] = hi;
    }
  };

  // prologue: stage tile 0
  stageA(0, 0);
  if (!BT) {
    stageB(0, 0);
  } else {
    loadV(0);
    writeV(0);
  }
  __syncthreads();

  const int wm = (w >> 1) * 64;
  const int wn = (w & 1) * 64;

  for (int kt = 0; kt < nk; ++kt) {
    const int cur = kt & 1;
    const int nxt = cur ^ 1;
    const bool more = (kt + 1) < nk;
    if (more) {
      stageA(nxt, (kt + 1) << 5);
      if (!BT)
        stageB(nxt, (kt + 1) << 5);
      else
        loadV((kt + 1) << 5);
    }
    f16x8 af[4], bf[4];
#pragma unroll
    for (int i = 0; i < 4; ++i)
      af[i] = *(const f16x8*)&As[cur][(wm + i * 16 + (ln & 15)) * BK +
                                      (ln >> 4) * 8];
#pragma unroll
    for (int j = 0; j < 4; ++j)
      bf[j] = *(const f16x8*)&Bs[cur][(wn + j * 16 + (ln & 15)) * BK +
                                      (ln >> 4) * 8];
#pragma unroll
    for (int i = 0; i < 4; ++i)
#pragma unroll
      for (int j = 0; j < 4; ++j)
        acc[i][j] =
            __builtin_amdgcn_mfma_f32_16x16x32_f16(af[i], bf[j], acc[i][j], 0, 0, 0);
    if (BT && more) writeV(nxt);
    __syncthreads();
  }

  // epilogue: C/D layout col = ln&15, row = (ln>>4)*4 + r   [m89-verified]
  const int lq = ln >> 4;
  const int lc = ln & 15;
#pragma unroll
  for (int i = 0; i < 4; ++i) {
#pragma unroll
    for (int j = 0; j < 4; ++j) {
      const int col = n0 + wn + j * 16 + lc;
      const float bv = BIAS ? bias[col] : 0.0f;
#pragma unroll
      for (int r = 0; r < 4; ++r) {
        const int row = m0 + wm + i * 16 + lq * 4 + r;
        float c = acc[i][j][r];
        if (MASK) c = (col >= vlen) ? -1000000.0f : c * scale;
        if (BIAS) c += bv;
        if (PERM) {
          const long idx =
              ((long)bz * 2048 + 2 * col + (row >> 10)) * 1024 + (row & 1023);
          ((f16*)Cv)[idx] = (f16)c;
        } else {
          const long idx = (long)bz * strideC + (long)row * ldc + col;
          if (OUTF16)
            ((f16*)Cv)[idx] = (f16)c;
          else
            ((float*)Cv)[idx] = c;
        }
      }
    }
  }
}

__global__ __launch_bounds__(256) void softmax_rows(
    const float* __restrict__ S, f16* __restrict__ attn,
    const int* __restrict__ vlens) {
  const long row = blockIdx.x;
  const int b = (int)(row >> 11);
  const int vlen = vlens[b];
  const float* p = S + row * 2048;
  const int tid = threadIdx.x;
  const int wave = tid >> 6, lane = tid & 63;
  const int c0 = tid * 8;

  float v[8];
  if (c0 + 8 <= vlen) {
    const float4 a = *(const float4*)(p + c0);
    const float4 bq = *(const float4*)(p + c0 + 4);
    v[0] = a.x; v[1] = a.y; v[2] = a.z; v[3] = a.w;
    v[4] = bq.x; v[5] = bq.y; v[6] = bq.z; v[7] = bq.w;
  } else {
#pragma unroll
    for (int j = 0; j < 8; ++j)
      v[j] = (c0 + j < vlen) ? p[c0 + j] : -1000000.0f;
  }

  float mx = v[0];
#pragma unroll
  for (int j = 1; j < 8; ++j) mx = fmaxf(mx, v[j]);
#pragma unroll
  for (int o = 1; o < 64; o <<= 1) mx = fmaxf(mx, __shfl_xor(mx, o));
  __shared__ float redm[4];
  if (lane == 0) redm[wave] = mx;
  __syncthreads();
  mx = fmaxf(fmaxf(redm[0], redm[1]), fmaxf(redm[2], redm[3]));

  float s = 0.f;
#pragma unroll
  for (int j = 0; j < 8; ++j) {
    v[j] = __expf(v[j] - mx);
    s += v[j];
  }
#pragma unroll
  for (int o = 1; o < 64; o <<= 1) s += __shfl_xor(s, o);
  __shared__ float reds[4];
  if (lane == 0) reds[wave] = s;
  __syncthreads();
  s = reds[0] + reds[1] + reds[2] + reds[3];

  const float inv = 1.0f / s;
  f16x8 ov;
#pragma unroll
  for (int j = 0; j < 8; ++j) ov[j] = (f16)(v[j] * inv);
  *(f16x8*)(attn + row * 2048 + c0) = ov;
}

__global__ __launch_bounds__(256) void cvt_f32_f16(const float* __restrict__ s,
                                                   f16* __restrict__ d, int n) {
  const int i = (blockIdx.x * 256 + threadIdx.x) * 8;
  if (i >= n) return;
  const float4 a = *(const float4*)(s + i);
  const float4 b = *(const float4*)(s + i + 4);
  f16x8 o;
  o[0] = (f16)a.x; o[1] = (f16)a.y; o[2] = (f16)a.z; o[3] = (f16)a.w;
  o[4] = (f16)b.x; o[5] = (f16)b.y; o[6] = (f16)b.z; o[7] = (f16)b.w;
  *(f16x8*)(d + i) = o;
}

extern "C" void kernel_launch(void* const* d_in, const int* in_sizes, int n_in,
                              void* d_out, int out_size, void* d_ws,
                              size_t ws_size, hipStream_t stream) {
  const float* X = (const float*)d_in[0];      // (4,2048,1024)
  const int* vlens = (const int*)d_in[1];      // (4,)
  const float* Wkqv = (const float*)d_in[2];   // (3072,1024)
  const float* bkqv = (const float*)d_in[3];   // (3072,)
  const float* Wproj = (const float*)d_in[4];  // (1024,1024)
  const float* bproj = (const float*)d_in[5];  // (1024,)
  float* out = (float*)d_out;                  // (4,2048,1024) f32

  char* w = (char*)d_ws;
  f16* Xh = (f16*)w;      w += 8192L * 1024 * 2;
  f16* Wkqvh = (f16*)w;   w += 3072L * 1024 * 2;
  f16* Wprojh = (f16*)w;  w += 1024L * 1024 * 2;
  f16* kqvh = (f16*)w;    w += 8192L * 3072 * 2;
  f16* attnh = (f16*)w;   w += 4L * 2048 * 2048 * 2;
  f16* out2h = (f16*)w;   w += 8192L * 1024 * 2;
  float* S = (float*)w;   // 4*2048*2048 f32

  cvt_f32_f16<<<4096, 256, 0, stream>>>(X, Xh, 8192 * 1024);
  cvt_f32_f16<<<1536, 256, 0, stream>>>(Wkqv, Wkqvh, 3072 * 1024);
  cvt_f32_f16<<<512, 256, 0, stream>>>(Wproj, Wprojh, 1024 * 1024);

  // G1: kqvh = f16(Xh @ Wkqvh^T + bkqv)   M=8192 N=3072 K=1024
  mfma_gemm<false, true, false, false, true, false>
      <<<dim3(24, 64, 1), 256, 0, stream>>>(Xh, 1024, Wkqvh, 1024, kqvh, 3072,
                                            bkqv, nullptr, 1.0f, 1024, 0, 0, 0);

  // G2: S[b] = Qh @ Kh^T * 1/32, masked   M=N=2048 K=1024 (per batch)
  mfma_gemm<false, false, true, false, false, false>
      <<<dim3(16, 16, 4), 256, 0, stream>>>(
          kqvh + 1024, 3072, kqvh, 3072, S, 2048, nullptr, vlens, 0.03125f,
          1024, 2048L * 3072, 2048L * 3072, 2048L * 2048);

  // SM: softmax rows, write fp16 attn
  softmax_rows<<<8192, 256, 0, stream>>>(S, attnh, vlens);

  // G4: out2h = f16(perm(attn @ V))   M=2048 N=1024 K=2048 (vlen-limited)
  mfma_gemm<true, false, false, true, true, true>
      <<<dim3(8, 16, 4), 256, 0, stream>>>(
          attnh, 2048, kqvh + 2048, 3072, out2h, 1024, nullptr, vlens, 1.0f,
          2048, 2048L * 2048, 2048L * 3072, 2048L * 1024);

  // G5: out = out2h @ Wprojh^T + bproj   M=8192 N=1024 K=1024 (f32 out)
  mfma_gemm<false, true, false, false, false, false>
      <<<dim3(8, 64, 1), 256, 0, stream>>>(out2h, 1024, Wprojh, 1024, out, 1024,
                                           bproj, nullptr, 1.0f, 1024, 0, 0, 0);
}